// Round 3
// baseline (100.413 us; speedup 1.0000x reference)
//
#include <hip/hip_runtime.h>
#include <hip/hip_bf16.h>

// TripletLoss batch-hard mining, B=8192, D=256.
// R5: traffic-minimal geometry. mine: BI=512 (8 waves/block, 512 thr),
//     grid 16x16 = 256 blocks = 1/CU exact; Xbt re-read traffic 192->128 MB.
//     norm: register-resident (no LDS, no barriers), same summation element
//     order as R2. Inner mining arithmetic byte-identical to R2/R4.

constexpr int NB = 8192;
constexpr int ND = 256;
constexpr int BI = 512;               // rows per block (8 waves x 64 rows)
constexpr int BJ = 64;                // cols per iteration
constexpr int JSPLIT = 16;            // grid.y
constexpr int JRANGE = NB / JSPLIT;   // 512
constexpr int NITER = JRANGE / BJ;    // 8

typedef __attribute__((ext_vector_type(8))) short bf16x8;
typedef __attribute__((ext_vector_type(4))) float f32x4;

typedef __attribute__((address_space(3))) unsigned int lds_u32;
typedef __attribute__((address_space(1))) const unsigned int g_u32;

__device__ inline void load_lds16(const unsigned short* g, unsigned short* l) {
    __builtin_amdgcn_global_load_lds((g_u32*)g, (lds_u32*)l, 16, 0, 0);
}

__device__ inline unsigned short f2bf(float v) {
    __hip_bfloat16 b = __float2bfloat16(v);
    return *reinterpret_cast<unsigned short*>(&b);
}

// ---------------- Kernel 1: normalize rows -> bf16, CHUNK-MAJOR ------------
// Register-resident: 8 threads/row, 32 floats/thread, butterfly row reduce.
// Partial-sum element order identical to R2 (thread e sums row elems
// e*32..e*32+31 in order); only the 8-partial combine order differs (ULP).
__global__ __launch_bounds__(256) void norm_kernel(const float* __restrict__ X,
                                                   unsigned short* __restrict__ Xbt,
                                                   float* accum, int* done) {
    const int t = threadIdx.x;
    const int rb = blockIdx.x * 32;
    const int r = t >> 3, e = t & 7;
    if (blockIdx.x == 0 && t == 0) { accum[0] = 0.f; accum[1] = 0.f; *done = 0; }

    const float4* src = (const float4*)(X + (size_t)(rb + r) * ND + e * 32);
    float4 v[8];
    #pragma unroll
    for (int k = 0; k < 8; k++) v[k] = src[k];

    float s = 0.f;
    #pragma unroll
    for (int k = 0; k < 8; k++) {
        s += v[k].x * v[k].x; s += v[k].y * v[k].y;
        s += v[k].z * v[k].z; s += v[k].w * v[k].w;
    }
    // reduce the 8 partials of this row (lanes differing in bits 0..2)
    #pragma unroll
    for (int m = 1; m <= 4; m <<= 1) s += __shfl_xor(s, m, 64);
    const float sc = 1.0f / fmaxf(sqrtf(s), 1e-12f);

    // thread owns chunks c = e*4+k (8 bf16 each); store chunk-major
    #pragma unroll
    for (int k = 0; k < 4; k++) {
        const float* f = (const float*)&v[2 * k];
        unsigned short tmp[8];
        #pragma unroll
        for (int q = 0; q < 8; q++) tmp[q] = f2bf(f[q] * sc);
        *(bf16x8*)(Xbt + ((size_t)(e * 4 + k) * NB + rb + r) * 8) = *(bf16x8*)tmp;
    }
}

// ---------------- Kernel 2: Gram + hard mining ------------------------------
// 8 waves/block; wave owns 64 rows (4 x 16), K=256 of A in registers.
// B-tile (64 cols) staged in LDS in READ-ORDER: region rg = kc*4+nf holds,
// at lane L*16B:  B[col = nf*16 + (L&15)][kchunk = kc*4 + (L>>4)]
// => every ds_read_b128 is lane-sequential (conflict-free).
// Mining key: key = s + 8*min(|lrow-lcol|,1); min(key)=hardest-pos sim,
// max(key)=8+hardest-neg sim. Diagonal (s~1) can never win the pos-min.
__global__ __launch_bounds__(512, 2) void mine_kernel(
    const unsigned short* __restrict__ Xbt, const int* __restrict__ labels,
    float* __restrict__ posP, float* __restrict__ negP) {
    __shared__ __align__(16) unsigned short Bt[2][32 * 512];  // 64 KB dbuf
    __shared__ float Lall[JRANGE];                            // 2 KB labels

    const int tid = threadIdx.x;
    const int w = tid >> 6;           // 0..7
    const int lane = tid & 63;
    const int quad = lane >> 4;
    const int l16 = lane & 15;

    const int rowbase = blockIdx.x * BI + w * 64;
    const int jstart = blockIdx.y * JRANGE;

    // one-time preload of all 512 column labels for this split
    Lall[tid] = (float)labels[jstart + tid];

    // A fragments: afrag[rs][kc] = 16B of row (rowbase+rs*16+l16), chunk (kc*4+quad)
    bf16x8 afrag[4][8];
    #pragma unroll
    for (int rs = 0; rs < 4; rs++)
        #pragma unroll
        for (int kc = 0; kc < 8; kc++) {
            const size_t u = (size_t)(kc * 4 + quad) * NB + (rowbase + rs * 16 + l16);
            afrag[rs][kc] = *(const bf16x8*)(Xbt + u * 8);
        }

    float flr[4][4];
    float minK[4][4], maxK[4][4];
    #pragma unroll
    for (int rs = 0; rs < 4; rs++)
        #pragma unroll
        for (int r = 0; r < 4; r++) {
            flr[rs][r] = (float)labels[rowbase + rs * 16 + quad * 4 + r];
            minK[rs][r] = 1e30f;
            maxK[rs][r] = -1e30f;
        }

    auto stage = [&](int buf, int jt) {
        const int jbase = jstart + jt * BJ;
        #pragma unroll
        for (int s = 0; s < 4; s++) {
            const int rg = w * 4 + s;                 // 32 regions over 8 waves
            const int kc = rg >> 2, nfi = rg & 3;
            const size_t u = (size_t)(kc * 4 + quad) * NB + (jbase + nfi * 16 + l16);
            load_lds16(Xbt + u * 8, &Bt[buf][rg * 512]);
        }
    };

    stage(0, 0);
    __syncthreads();   // Bt[0], Lall ready

    for (int jt = 0; jt < NITER; jt++) {
        const int cur = jt & 1;
        if (jt + 1 < NITER) stage(cur ^ 1, jt + 1);   // async; lands under MFMA

        #pragma unroll
        for (int nf = 0; nf < 4; nf++) {
            const float flc = Lall[jt * BJ + nf * 16 + l16];
            f32x4 acc[4];
            #pragma unroll
            for (int rs = 0; rs < 4; rs++) acc[rs] = (f32x4){0.f, 0.f, 0.f, 0.f};
            #pragma unroll
            for (int kc = 0; kc < 8; kc++) {
                const bf16x8 b = *(const bf16x8*)(&Bt[cur][(kc * 4 + nf) * 512 + lane * 8]);
                #pragma unroll
                for (int rs = 0; rs < 4; rs++)
                    acc[rs] = __builtin_amdgcn_mfma_f32_16x16x32_bf16(
                        afrag[rs][kc], b, acc[rs], 0, 0, 0);
            }
            #pragma unroll
            for (int rs = 0; rs < 4; rs++)
                #pragma unroll
                for (int r = 0; r < 4; r++) {
                    const float d = flr[rs][r] - flc;
                    const float uu = fminf(fabsf(d), 1.0f);
                    const float key = fmaf(uu, 8.0f, acc[rs][r]);
                    minK[rs][r] = fminf(minK[rs][r], key);
                    maxK[rs][r] = fmaxf(maxK[rs][r], key);
                }
        }
        __syncthreads();  // stage(jt+1) landed; Bt[cur] free for overwrite
    }

    // reduce across the 16 lanes (bits 0..3) sharing each row
    #pragma unroll
    for (int rs = 0; rs < 4; rs++)
        #pragma unroll
        for (int r = 0; r < 4; r++) {
            float p = minK[rs][r], n = maxK[rs][r];
            #pragma unroll
            for (int m = 1; m <= 8; m <<= 1) {
                p = fminf(p, __shfl_xor(p, m, 64));
                n = fmaxf(n, __shfl_xor(n, m, 64));
            }
            if (l16 == 0) {
                const int row = rowbase + rs * 16 + quad * 4 + r;
                posP[blockIdx.y * NB + row] = p;
                negP[blockIdx.y * NB + row] = n;
            }
        }
}

// ---------------- Kernel 3: combine splits, hinge, global reduce, finalize --
__global__ __launch_bounds__(256) void finish_kernel(
    const float* __restrict__ posP, const float* __restrict__ negP,
    float* accum, int* done, float* __restrict__ out) {
    const int i = blockIdx.x * 256 + threadIdx.x;
    float p = 1e30f, n = -1e30f;
    #pragma unroll
    for (int s = 0; s < JSPLIT; s++) {
        p = fminf(p, posP[s * NB + i]);
        n = fmaxf(n, negP[s * NB + i]);
    }
    // p < 4: some positive existed; n > 4: some negative existed (key = s+8)
    const bool valid = (p < 4.0f) && (n > 4.0f);
    const float pos_d = fmaxf(1.0f - p, 0.0f);
    const float neg_d = fmaxf(1.0f - (n - 8.0f), 0.0f);
    float per = valid ? fmaxf(pos_d - neg_d + 1.0f, 0.0f) : 0.0f;
    float cnt = valid ? 1.0f : 0.0f;
    #pragma unroll
    for (int off = 32; off > 0; off >>= 1) {
        per += __shfl_down(per, off, 64);
        cnt += __shfl_down(cnt, off, 64);
    }
    __shared__ float sp[4], sc[4];
    const int wv = threadIdx.x >> 6, ln = threadIdx.x & 63;
    if (ln == 0) { sp[wv] = per; sc[wv] = cnt; }
    __syncthreads();
    if (threadIdx.x == 0) {
        atomicAdd(&accum[0], sp[0] + sp[1] + sp[2] + sp[3]);
        atomicAdd(&accum[1], sc[0] + sc[1] + sc[2] + sc[3]);
        __threadfence();
        const int old = atomicAdd(done, 1);
        if (old == (int)gridDim.x - 1) {
            const float s = __hip_atomic_load(&accum[0], __ATOMIC_RELAXED,
                                              __HIP_MEMORY_SCOPE_AGENT);
            const float c = __hip_atomic_load(&accum[1], __ATOMIC_RELAXED,
                                              __HIP_MEMORY_SCOPE_AGENT);
            out[0] = (c > 0.f) ? s / fmaxf(c, 1.f) : 0.f;
        }
    }
}

// ---------------- launcher --------------------------------------------------
extern "C" void kernel_launch(void* const* d_in, const int* in_sizes, int n_in,
                              void* d_out, int out_size, void* d_ws, size_t ws_size,
                              hipStream_t stream) {
    const float* X = (const float*)d_in[0];
    const int* labels = (const int*)d_in[1];
    float* out = (float*)d_out;

    char* ws = (char*)d_ws;
    unsigned short* Xbt = (unsigned short*)ws;                    // 4 MB
    float* posP = (float*)(ws + (size_t)4 * 1024 * 1024);         // 512 KB
    float* negP = posP + JSPLIT * NB;                             // 512 KB
    float* accum = negP + JSPLIT * NB;                            // 8 B
    int* done = (int*)(accum + 2);                                // 4 B

    norm_kernel<<<NB / 32, 256, 0, stream>>>(X, Xbt, accum, done);
    mine_kernel<<<dim3(NB / BI, JSPLIT), 512, 0, stream>>>(
        (const unsigned short*)Xbt, labels, posP, negP);
    finish_kernel<<<NB / 256, 256, 0, stream>>>(posP, negP, accum, done, out);
}

// Round 4
// 97.053 us; speedup vs baseline: 1.0346x; 1.0346x over previous
//
#include <hip/hip_runtime.h>
#include <hip/hip_bf16.h>

// TripletLoss batch-hard mining, B=8192, D=256.
// R6: occupancy 2->4 waves/SIMD. Wave owns 32 rows (afrag[2][8] = 64 VGPR,
//     total ~120 => 4 waves/SIMD at <=128 VGPR cap). 8-wave blocks, BI=256,
//     grid (32,16) = 2 blocks/CU x 8 waves = 16 waves/CU. Staging/dbuf and
//     mining arithmetic byte-identical to R5; only rs extents / row map.

constexpr int NB = 8192;
constexpr int ND = 256;
constexpr int BI = 256;               // rows per block (8 waves x 32 rows)
constexpr int BJ = 64;                // cols per iteration
constexpr int JSPLIT = 16;            // grid.y
constexpr int JRANGE = NB / JSPLIT;   // 512
constexpr int NITER = JRANGE / BJ;    // 8

typedef __attribute__((ext_vector_type(8))) short bf16x8;
typedef __attribute__((ext_vector_type(4))) float f32x4;

typedef __attribute__((address_space(3))) unsigned int lds_u32;
typedef __attribute__((address_space(1))) const unsigned int g_u32;

__device__ inline void load_lds16(const unsigned short* g, unsigned short* l) {
    __builtin_amdgcn_global_load_lds((g_u32*)g, (lds_u32*)l, 16, 0, 0);
}

__device__ inline unsigned short f2bf(float v) {
    __hip_bfloat16 b = __float2bfloat16(v);
    return *reinterpret_cast<unsigned short*>(&b);
}

// ---------------- Kernel 1: normalize rows -> bf16, CHUNK-MAJOR ------------
// Register-resident: 8 threads/row, 32 floats/thread, butterfly row reduce.
__global__ __launch_bounds__(256) void norm_kernel(const float* __restrict__ X,
                                                   unsigned short* __restrict__ Xbt,
                                                   float* accum, int* done) {
    const int t = threadIdx.x;
    const int rb = blockIdx.x * 32;
    const int r = t >> 3, e = t & 7;
    if (blockIdx.x == 0 && t == 0) { accum[0] = 0.f; accum[1] = 0.f; *done = 0; }

    const float4* src = (const float4*)(X + (size_t)(rb + r) * ND + e * 32);
    float4 v[8];
    #pragma unroll
    for (int k = 0; k < 8; k++) v[k] = src[k];

    float s = 0.f;
    #pragma unroll
    for (int k = 0; k < 8; k++) {
        s += v[k].x * v[k].x; s += v[k].y * v[k].y;
        s += v[k].z * v[k].z; s += v[k].w * v[k].w;
    }
    #pragma unroll
    for (int m = 1; m <= 4; m <<= 1) s += __shfl_xor(s, m, 64);
    const float sc = 1.0f / fmaxf(sqrtf(s), 1e-12f);

    #pragma unroll
    for (int k = 0; k < 4; k++) {
        const float* f = (const float*)&v[2 * k];
        unsigned short tmp[8];
        #pragma unroll
        for (int q = 0; q < 8; q++) tmp[q] = f2bf(f[q] * sc);
        *(bf16x8*)(Xbt + ((size_t)(e * 4 + k) * NB + rb + r) * 8) = *(bf16x8*)tmp;
    }
}

// ---------------- Kernel 2: Gram + hard mining ------------------------------
// 8 waves/block; wave owns 32 rows (2 x 16), K=256 of A in registers (64 VGPR).
// B-tile (64 cols) staged in LDS in READ-ORDER: region rg = kc*4+nf holds,
// at lane L*16B:  B[col = nf*16 + (L&15)][kchunk = kc*4 + (L>>4)]
// => every ds_read_b128 is lane-sequential (conflict-free).
// Mining key: key = s + 8*min(|lrow-lcol|,1); min(key)=hardest-pos sim,
// max(key)=8+hardest-neg sim. Diagonal (s~1) can never win the pos-min.
__global__ __launch_bounds__(512, 4) void mine_kernel(
    const unsigned short* __restrict__ Xbt, const int* __restrict__ labels,
    float* __restrict__ posP, float* __restrict__ negP) {
    __shared__ __align__(16) unsigned short Bt[2][32 * 512];  // 64 KB dbuf
    __shared__ float Lall[JRANGE];                            // 2 KB labels

    const int tid = threadIdx.x;
    const int w = tid >> 6;           // 0..7
    const int lane = tid & 63;
    const int quad = lane >> 4;
    const int l16 = lane & 15;

    const int rowbase = blockIdx.x * BI + w * 32;
    const int jstart = blockIdx.y * JRANGE;

    // one-time preload of all 512 column labels for this split
    Lall[tid] = (float)labels[jstart + tid];

    // A fragments: afrag[rs][kc] = 16B of row (rowbase+rs*16+l16), chunk (kc*4+quad)
    bf16x8 afrag[2][8];
    #pragma unroll
    for (int rs = 0; rs < 2; rs++)
        #pragma unroll
        for (int kc = 0; kc < 8; kc++) {
            const size_t u = (size_t)(kc * 4 + quad) * NB + (rowbase + rs * 16 + l16);
            afrag[rs][kc] = *(const bf16x8*)(Xbt + u * 8);
        }

    float flr[2][4];
    float minK[2][4], maxK[2][4];
    #pragma unroll
    for (int rs = 0; rs < 2; rs++)
        #pragma unroll
        for (int r = 0; r < 4; r++) {
            flr[rs][r] = (float)labels[rowbase + rs * 16 + quad * 4 + r];
            minK[rs][r] = 1e30f;
            maxK[rs][r] = -1e30f;
        }

    auto stage = [&](int buf, int jt) {
        const int jbase = jstart + jt * BJ;
        #pragma unroll
        for (int s = 0; s < 4; s++) {
            const int rg = w * 4 + s;                 // 32 regions over 8 waves
            const int kc = rg >> 2, nfi = rg & 3;
            const size_t u = (size_t)(kc * 4 + quad) * NB + (jbase + nfi * 16 + l16);
            load_lds16(Xbt + u * 8, &Bt[buf][rg * 512]);
        }
    };

    stage(0, 0);
    __syncthreads();   // Bt[0], Lall ready

    for (int jt = 0; jt < NITER; jt++) {
        const int cur = jt & 1;
        if (jt + 1 < NITER) stage(cur ^ 1, jt + 1);   // async; lands under MFMA

        #pragma unroll
        for (int nf = 0; nf < 4; nf++) {
            const float flc = Lall[jt * BJ + nf * 16 + l16];
            f32x4 acc[2];
            #pragma unroll
            for (int rs = 0; rs < 2; rs++) acc[rs] = (f32x4){0.f, 0.f, 0.f, 0.f};
            #pragma unroll
            for (int kc = 0; kc < 8; kc++) {
                const bf16x8 b = *(const bf16x8*)(&Bt[cur][(kc * 4 + nf) * 512 + lane * 8]);
                #pragma unroll
                for (int rs = 0; rs < 2; rs++)
                    acc[rs] = __builtin_amdgcn_mfma_f32_16x16x32_bf16(
                        afrag[rs][kc], b, acc[rs], 0, 0, 0);
            }
            #pragma unroll
            for (int rs = 0; rs < 2; rs++)
                #pragma unroll
                for (int r = 0; r < 4; r++) {
                    const float d = flr[rs][r] - flc;
                    const float uu = fminf(fabsf(d), 1.0f);
                    const float key = fmaf(uu, 8.0f, acc[rs][r]);
                    minK[rs][r] = fminf(minK[rs][r], key);
                    maxK[rs][r] = fmaxf(maxK[rs][r], key);
                }
        }
        __syncthreads();  // stage(jt+1) landed; Bt[cur] free for overwrite
    }

    // reduce across the 16 lanes (bits 0..3) sharing each row
    #pragma unroll
    for (int rs = 0; rs < 2; rs++)
        #pragma unroll
        for (int r = 0; r < 4; r++) {
            float p = minK[rs][r], n = maxK[rs][r];
            #pragma unroll
            for (int m = 1; m <= 8; m <<= 1) {
                p = fminf(p, __shfl_xor(p, m, 64));
                n = fmaxf(n, __shfl_xor(n, m, 64));
            }
            if (l16 == 0) {
                const int row = rowbase + rs * 16 + quad * 4 + r;
                posP[blockIdx.y * NB + row] = p;
                negP[blockIdx.y * NB + row] = n;
            }
        }
}

// ---------------- Kernel 3: combine splits, hinge, global reduce, finalize --
__global__ __launch_bounds__(256) void finish_kernel(
    const float* __restrict__ posP, const float* __restrict__ negP,
    float* accum, int* done, float* __restrict__ out) {
    const int i = blockIdx.x * 256 + threadIdx.x;
    float p = 1e30f, n = -1e30f;
    #pragma unroll
    for (int s = 0; s < JSPLIT; s++) {
        p = fminf(p, posP[s * NB + i]);
        n = fmaxf(n, negP[s * NB + i]);
    }
    // p < 4: some positive existed; n > 4: some negative existed (key = s+8)
    const bool valid = (p < 4.0f) && (n > 4.0f);
    const float pos_d = fmaxf(1.0f - p, 0.0f);
    const float neg_d = fmaxf(1.0f - (n - 8.0f), 0.0f);
    float per = valid ? fmaxf(pos_d - neg_d + 1.0f, 0.0f) : 0.0f;
    float cnt = valid ? 1.0f : 0.0f;
    #pragma unroll
    for (int off = 32; off > 0; off >>= 1) {
        per += __shfl_down(per, off, 64);
        cnt += __shfl_down(cnt, off, 64);
    }
    __shared__ float sp[4], sc[4];
    const int wv = threadIdx.x >> 6, ln = threadIdx.x & 63;
    if (ln == 0) { sp[wv] = per; sc[wv] = cnt; }
    __syncthreads();
    if (threadIdx.x == 0) {
        atomicAdd(&accum[0], sp[0] + sp[1] + sp[2] + sp[3]);
        atomicAdd(&accum[1], sc[0] + sc[1] + sc[2] + sc[3]);
        __threadfence();
        const int old = atomicAdd(done, 1);
        if (old == (int)gridDim.x - 1) {
            const float s = __hip_atomic_load(&accum[0], __ATOMIC_RELAXED,
                                              __HIP_MEMORY_SCOPE_AGENT);
            const float c = __hip_atomic_load(&accum[1], __ATOMIC_RELAXED,
                                              __HIP_MEMORY_SCOPE_AGENT);
            out[0] = (c > 0.f) ? s / fmaxf(c, 1.f) : 0.f;
        }
    }
}

// ---------------- launcher --------------------------------------------------
extern "C" void kernel_launch(void* const* d_in, const int* in_sizes, int n_in,
                              void* d_out, int out_size, void* d_ws, size_t ws_size,
                              hipStream_t stream) {
    const float* X = (const float*)d_in[0];
    const int* labels = (const int*)d_in[1];
    float* out = (float*)d_out;

    char* ws = (char*)d_ws;
    unsigned short* Xbt = (unsigned short*)ws;                    // 4 MB
    float* posP = (float*)(ws + (size_t)4 * 1024 * 1024);         // 512 KB
    float* negP = posP + JSPLIT * NB;                             // 512 KB
    float* accum = negP + JSPLIT * NB;                            // 8 B
    int* done = (int*)(accum + 2);                                // 4 B

    norm_kernel<<<NB / 32, 256, 0, stream>>>(X, Xbt, accum, done);
    mine_kernel<<<dim3(NB / BI, JSPLIT), 512, 0, stream>>>(
        (const unsigned short*)Xbt, labels, posP, negP);
    finish_kernel<<<NB / 256, 256, 0, stream>>>(posP, negP, accum, done, out);
}